// Round 5
// baseline (285.957 us; speedup 1.0000x reference)
//
#include <hip/hip_runtime.h>

// DVQ bottleneck: B=8, N=4096, D=1024, S=4, K=16, d=256, BETA=0.25
// Outputs (flat fp32 in d_out): z[8*4096*1024], ids_packed[32768] (as float),
// vq_total[1].
//
// R10: occupancy attack. R9 (512 thr, 80KB LDS) = 2 blocks/CU = 16 waves max,
// measured 34% occ, VALU 32%, HBM 26% -- convoy-bound, no pipe saturated.
// R10 keeps the verified tile/staging/swizzle/numerics and goes to
// 1024-thread blocks (16 waves): 2 blocks/CU = 32 waves/CU = 100% of the
// wave budget (needs VGPR<=64, enforced via __launch_bounds__(1024,8); R9
// was 52 with 2x the accumulators).
//   Wave split: (dh 0..7) x (kq 0..1): wave = 32 dims x 8 codebooks.
//   Reduce: two-stage. dh>=1 waves write dot partials to a [kk][wq][lane]
//   arena (57KB, aliases the dead h tile; contiguous 512B per instr = LDS
//   bank-optimal). dh=0 waves sum 7 partials + local argmin over their
//   contiguous k-range {kq*8..kq*8+7}; wave 0 merges 2 candidates with
//   strict < (lower-k set wins ties -> jnp argmin first-index preserved).
//   Loss: sum_t(ze2_t+best_t) decomposed as sum(ze2 chunk sums) + sum(best)
//   -- fp64 reassociation only, invisible in the fp32 output.
// Staging identical to R9 (global_load_lds w=16, linear LDS dest, XOR
// swizzle in the per-lane GLOBAL source address; full-coverage checked:
// h 16 waves x 4 rows = 64 rows, cb 16 waves x 1KB = 16KB).

#define D_FULL 1024
#define SEG 4
#define DSEG 256
#define KC 16

#define GLOBAL_AS __attribute__((address_space(1)))
#define LDS_AS __attribute__((address_space(3)))

static __device__ __forceinline__ void load_lds16(const void* g, void* l) {
    __builtin_amdgcn_global_load_lds((GLOBAL_AS const unsigned int*)g,
                                     (LDS_AS unsigned int*)l, 16, 0, 0);
}

// Prep (64 blocks x 256): fp64 ||c||^2 per (s,k), zero ids_out + loss
// (d_out/d_ws poisoned 0xAA before every timed launch).
__global__ __launch_bounds__(256) void dvq_prep(const float* __restrict__ cb,
                                                double* __restrict__ c2d,
                                                float* __restrict__ ids_out,
                                                float* __restrict__ loss_out) {
    __shared__ double ws[4];
    const int b = blockIdx.x;    // 0..63 == (s,k) pair
    const int t = threadIdx.x;
    const int lane = t & 63;
    const int w = t >> 6;

    ids_out[b * 512 + t] = 0.0f;
    ids_out[b * 512 + 256 + t] = 0.0f;
    if (b == 0 && t == 0) *loss_out = 0.0f;

    double v = (double)cb[b * 256 + t];
    double sq = v * v;
#pragma unroll
    for (int off = 32; off > 0; off >>= 1)
        sq += __shfl_down(sq, off, 64);
    if (lane == 0) ws[w] = sq;
    __syncthreads();
    if (t == 0) c2d[b] = ws[0] + ws[1] + ws[2] + ws[3];
}

__global__ __launch_bounds__(1024, 8) void dvq_main(
        const float* __restrict__ h, const float* __restrict__ cb,
        const double* __restrict__ c2d, float* __restrict__ z_out,
        float* __restrict__ ids_out, float* __restrict__ loss_out) {
    // hl: 64KB h tile [64 tokens][64 float4], XOR-swizzled (phys = j ^ tok).
    // After compute hl is dead and aliased by the reduce arenas:
    //   part  @0     : [8 kk][14 wq][64 lane] fp64 = 57344B
    //   cand_s@57344 : [2][64] fp64 = 1024B
    //   cand_k@58368 : [2][64] int  = 512B
    //   ze2s  @58880 : [8] fp64     = 64B
    //   ids_l @58944 : [64] int     = 256B   (total 59200 <= 65536)
    __shared__ __align__(16) float4 hl[64 * 64];
    __shared__ __align__(16) float cbl[KC * DSEG];  // 16KB fp32 codebook slice

    const int i = threadIdx.x;
    const int lane = i & 63;                           // token within block
    const int w = i >> 6;                              // wave id (0..15)
    const int ch = __builtin_amdgcn_readfirstlane(w);  // wave-uniform SGPR
    const int chd = ch >> 1;                           // dim-chunk 0..7 (32 dims)
    const int ckq = ch & 1;                            // k-half 0..1 (8 ks)

    const int s = blockIdx.x & 3;                      // segment
    const long tok_base = (long)(blockIdx.x >> 2) * 64;

    char* hl_b = (char*)hl;
    char* cbl_b = (char*)cbl;

    // ---- Async staging: 4 h rows + 1KB of cb per wave (global_load_lds).
    // LDS dest linear; XOR swizzle in the per-lane GLOBAL source address. ----
#pragma unroll
    for (int rr = 0; rr < 4; ++rr) {
        const int r = ch * 4 + rr;
        load_lds16(h + (tok_base + r) * D_FULL + (long)s * DSEG +
                       ((lane ^ r) << 2),
                   hl_b + r * 1024);
    }
    load_lds16(cb + s * (KC * DSEG) + ch * 256 + lane * 4, cbl_b + ch * 1024);

    __syncthreads();  // compiler drains vmcnt(0) before s_barrier

    // ---- Phase 1: fp64 partial dots. lane = token; wave = 32 dims x 8 ks. ----
    const int k0 = ckq * 8;
    const int tk = lane;

    double dot[8];
#pragma unroll
    for (int kk = 0; kk < 8; ++kk) dot[kk] = 0.0;
    double ze2 = 0.0;

#pragma unroll
    for (int j = 0; j < 8; ++j) {
        const int jj = chd * 8 + j;                 // logical float4 col
        float4 z4 = hl[tk * 64 + (jj ^ tk)];        // swizzled read
        double z0 = (double)z4.x, z1 = (double)z4.y;
        double z2 = (double)z4.z, z3 = (double)z4.w;
        if (ckq == 0) {                             // wave-uniform branch
            ze2 = fma(z0, z0, ze2);
            ze2 = fma(z1, z1, ze2);
            ze2 = fma(z2, z2, ze2);
            ze2 = fma(z3, z3, ze2);
        }
#pragma unroll
        for (int kk = 0; kk < 8; ++kk) {
            float4 c4 = *(const float4*)(cbl + (k0 + kk) * DSEG + jj * 4);
            double a = dot[kk];
            a = fma(z0, (double)c4.x, a);
            a = fma(z1, (double)c4.y, a);
            a = fma(z2, (double)c4.z, a);
            a = fma(z3, (double)c4.w, a);
            dot[kk] = a;
        }
    }

    // ---- Stage-1 reduce: dh>=1 waves dump partials (hl reads done) ----
    __syncthreads();
    double* part   = (double*)hl_b;             // [8][14][64]
    double* cand_s = (double*)(hl_b + 57344);   // [2][64]
    int*    cand_k = (int*)(hl_b + 58368);      // [2][64]
    double* ze2s   = (double*)(hl_b + 58880);   // [8]
    int*    ids_l  = (int*)(hl_b + 58944);      // [64]

    if (ch >= 2) {
        const int wq = (chd - 1) * 2 + ckq;     // 0..13
#pragma unroll
        for (int kk = 0; kk < 8; ++kk)
            part[(kk * 14 + wq) * 64 + lane] = dot[kk];
    }
    if (ckq == 0) {
        // block-wide ze2 contribution of this 32-dim chunk (sum over tokens)
        double t = ze2;
#pragma unroll
        for (int off = 32; off > 0; off >>= 1)
            t += __shfl_down(t, off, 64);
        if (lane == 0) ze2s[chd] = t;
    }
    __syncthreads();

    // ---- Stage-2 reduce: dh==0 waves sum 7 partials, local argmin ----
    if (ch < 2) {
#pragma unroll
        for (int kk = 0; kk < 8; ++kk) {
#pragma unroll
            for (int c = 0; c < 7; ++c)
                dot[kk] += part[(kk * 14 + (c * 2 + ckq)) * 64 + lane];
        }
        const double* c2s = c2d + s * KC;  // 128B, scalar loads
        double best = c2s[k0] - 2.0 * dot[0];
        int bk = k0;
#pragma unroll
        for (int kk = 1; kk < 8; ++kk) {
            double sc = c2s[k0 + kk] - 2.0 * dot[kk];
            if (sc < best) { best = sc; bk = k0 + kk; }  // strict <: first-index
        }
        cand_s[ckq * 64 + lane] = best;
        cand_k[ckq * 64 + lane] = bk;
    }
    __syncthreads();

    // ---- Final merge on wave 0 (strict <: lower-k set wins ties) ----
    if (ch == 0) {
        double s0 = cand_s[lane];
        int b0 = cand_k[lane];
        double s1 = cand_s[64 + lane];
        int b1 = cand_k[64 + lane];
        double best = s0; int bk = b0;
        if (s1 < best) { best = s1; bk = b1; }
        ids_l[lane] = bk;

        // ids_packed contribution: bk * 16^s, exact in fp32 (<= 61440)
        atomicAdd(&ids_out[tok_base + lane], (float)(bk << (4 * s)));

        // loss: sum_t(ze2_t + best_t) = sum(ze2 chunks) + sum(best)
        double t = best;
#pragma unroll
        for (int off = 32; off > 0; off >>= 1)
            t += __shfl_down(t, off, 64);
        if (lane == 0) {
            double zs = 0.0;
#pragma unroll
            for (int q = 0; q < 8; ++q) zs += ze2s[q];
            atomicAdd(loss_out, (float)((t + zs) * (1.25 / 8388608.0)));
        }
    }
    __syncthreads();  // ids_l visible to all waves

    // ---- Phase 2: z write from LDS codebook, 4 rows/wave, 1KB coalesced ----
    const float4* cbl4 = (const float4*)cbl;
#pragma unroll
    for (int r0 = 0; r0 < 4; ++r0) {
        int r = ch * 4 + r0;
        int k = ids_l[r];                      // wave-uniform broadcast
        float4 v = cbl4[k * 64 + lane];        // contiguous 1KB, bank-optimal
        ((float4*)(z_out + (tok_base + r) * D_FULL + (long)s * DSEG))[lane] = v;
    }
}

extern "C" void kernel_launch(void* const* d_in, const int* in_sizes, int n_in,
                              void* d_out, int out_size, void* d_ws, size_t ws_size,
                              hipStream_t stream) {
    const float* h  = (const float*)d_in[0];
    const float* cb = (const float*)d_in[1];

    const int n_h = in_sizes[0];          // 33554432
    const int tokens = n_h / D_FULL;      // 32768

    float* z_out    = (float*)d_out;
    float* ids_out  = z_out + (size_t)n_h;
    float* loss_out = ids_out + tokens;

    double* c2d = (double*)d_ws;          // 64 doubles

    dvq_prep<<<64, 256, 0, stream>>>(cb, c2d, ids_out, loss_out);
    dvq_main<<<(tokens / 64) * SEG, 1024, 0, stream>>>(h, cb, c2d, z_out,
                                                       ids_out, loss_out);
}

// Round 6
// 275.656 us; speedup vs baseline: 1.0374x; 1.0374x over previous
//
#include <hip/hip_runtime.h>

// DVQ bottleneck: B=8, N=4096, D=1024, S=4, K=16, d=256, BETA=0.25
// Outputs (flat fp32 in d_out): z[8*4096*1024], ids_packed[32768] (as float),
// vq_total[1].
//
// R11: R10 regressed (97->129us): launch_bounds(1024,8) forced VGPR<=64 ->
// fp64 accumulators spilled to scratch (WRITE 131->328MB, FETCH 66->114MB).
// Reverted. Re-derived R9's budget WITH the LDS pipe: 17 ds_read_b128 per
// j-step per wave (1 z + 16 cb broadcasts) = 1088/block ~ 43us/CU serialized
// -- an LDS-instruction wall (conflict-free, so invisible in BANK_CONFLICT),
// plus ~31us fp64 VALU. R11 removes both, keeping R9's proven skeleton
// (512thr/8 waves, 64-tok tile, global_load_lds + XOR swizzle, arena alias):
//   (a) cb reads moved from LDS to GLOBAL wave-uniform loads -> compiler
//       emits s_loads via the scalar K$ (no LDS pipe, no VALU). R5's K$
//       thrash was 32KB fp64 x 4 interleaved segments; now 16KB fp32 and
//       the grid is SEGMENT-MAJOR (s = blockIdx>>9) so a CU sees one slice.
//   (b) fp32 chunk dots (32-dim chunks) + fp64 chunk-combine + fp64 scores;
//       near-ties (second-best < 1e-3, bound ratio >=4x, ~1/block expected)
//       are RESCUED by a wave-cooperative exact-fp64 recompute (lane =
//       k x dim-chunk, shuffle reduce, strict-< / lower-k tie-break), so the
//       final argmin is provably identical to the all-fp64 kernel.
//   (c) LDS = 64KB h tile only; fp32 arena [7][64][17] (30.5KB) aliases it.
//       Phase-2 z rows read from global cb (L2-resident, 1KB coalesced).
// Loss uses the approx best (|err|<1e-3 per token on a ~3e7 sum: invisible).

#define D_FULL 1024
#define SEG 4
#define DSEG 256
#define KC 16
#define EPS_RESCUE 1e-3

#define GLOBAL_AS __attribute__((address_space(1)))
#define LDS_AS __attribute__((address_space(3)))

static __device__ __forceinline__ void load_lds16(const void* g, void* l) {
    __builtin_amdgcn_global_load_lds((GLOBAL_AS const unsigned int*)g,
                                     (LDS_AS unsigned int*)l, 16, 0, 0);
}

// Prep (64 blocks x 256): fp64 ||c||^2 per (s,k), zero ids_out + loss
// (d_out/d_ws poisoned 0xAA before every timed launch).
__global__ __launch_bounds__(256) void dvq_prep(const float* __restrict__ cb,
                                                double* __restrict__ c2d,
                                                float* __restrict__ ids_out,
                                                float* __restrict__ loss_out) {
    __shared__ double ws[4];
    const int b = blockIdx.x;    // 0..63 == (s,k) pair
    const int t = threadIdx.x;
    const int lane = t & 63;
    const int w = t >> 6;

    ids_out[b * 512 + t] = 0.0f;
    ids_out[b * 512 + 256 + t] = 0.0f;
    if (b == 0 && t == 0) *loss_out = 0.0f;

    double v = (double)cb[b * 256 + t];
    double sq = v * v;
#pragma unroll
    for (int off = 32; off > 0; off >>= 1)
        sq += __shfl_down(sq, off, 64);
    if (lane == 0) ws[w] = sq;
    __syncthreads();
    if (t == 0) c2d[b] = ws[0] + ws[1] + ws[2] + ws[3];
}

__global__ __launch_bounds__(512, 4) void dvq_main(const float* __restrict__ h,
                                                   const float* __restrict__ cb,
                                                   const double* __restrict__ c2d,
                                                   float* __restrict__ z_out,
                                                   float* __restrict__ ids_out,
                                                   float* __restrict__ loss_out) {
    // hl: 64KB h tile [64 tokens][64 float4], XOR-swizzled (phys = j ^ tok).
    // After compute it is aliased by: part [7][64][17] fp32 = 30464B,
    // ids_l [64] int at byte 30720.
    __shared__ __align__(16) float4 hl[64 * 64];

    const int i = threadIdx.x;
    const int lane = i & 63;                           // token within block
    const int w = i >> 6;                              // wave id == d-chunk (0..7)
    const int ch = __builtin_amdgcn_readfirstlane(w);  // wave-uniform SGPR

    const int s = blockIdx.x >> 9;                     // SEGMENT-MAJOR grid
    const long tok_base = (long)(blockIdx.x & 511) * 64;

    char* hl_b = (char*)hl;

    // ---- Async staging: 8 h rows per wave (global_load_lds w=16).
    // LDS dest linear; XOR swizzle in the per-lane GLOBAL source address. ----
#pragma unroll
    for (int rr = 0; rr < 8; ++rr) {
        const int r = ch * 8 + rr;
        load_lds16(h + (tok_base + r) * D_FULL + (long)s * DSEG +
                       ((lane ^ r) << 2),
                   hl_b + r * 1024);
    }
    __syncthreads();  // compiler drains vmcnt(0) before s_barrier

    // ---- Phase 1: fp32 chunk dots. lane = token, wave = 32-dim chunk.
    // z via swizzled LDS read; cb via wave-uniform GLOBAL reads (s_load/K$).
    const float* cbseg = cb + s * (KC * DSEG);
    const int tk = lane;

    float dot[KC];
#pragma unroll
    for (int k = 0; k < KC; ++k) dot[k] = 0.0f;
    float ze2 = 0.0f;

#pragma unroll
    for (int j = 0; j < 8; ++j) {
        const int jj = ch * 8 + j;                  // logical float4 col (uniform)
        float4 z4 = hl[tk * 64 + (jj ^ tk)];        // swizzled read
        ze2 = fmaf(z4.x, z4.x, ze2);
        ze2 = fmaf(z4.y, z4.y, ze2);
        ze2 = fmaf(z4.z, z4.z, ze2);
        ze2 = fmaf(z4.w, z4.w, ze2);
#pragma unroll
        for (int k = 0; k < KC; ++k) {
            const float4 c4 = *(const float4*)(cbseg + k * DSEG + jj * 4);
            dot[k] = fmaf(z4.x, c4.x, dot[k]);
            dot[k] = fmaf(z4.y, c4.y, dot[k]);
            dot[k] = fmaf(z4.z, c4.z, dot[k]);
            dot[k] = fmaf(z4.w, c4.w, dot[k]);
        }
    }

    // ---- Cross-wave reduction: fp32 partials alias the h tile ----
    __syncthreads();  // all waves finished reading hl
    float* part  = (float*)hl_b;                // [7][64][17] fp32
    int*   ids_l = (int*)(hl_b + 30720);        // [64]

    if (w != 0) {
        float* p = part + ((w - 1) * 64 + lane) * (KC + 1);
#pragma unroll
        for (int k = 0; k < KC; ++k) p[k] = dot[k];
        p[KC] = ze2;
    }
    __syncthreads();

    if (w == 0) {
        // fp64 combine of 8 fp32 chunk-dots: error <= ~1.2e-4 per score.
        double d64[KC];
#pragma unroll
        for (int k = 0; k < KC; ++k) d64[k] = (double)dot[k];
        double z64 = (double)ze2;
#pragma unroll
        for (int c = 0; c < 7; ++c) {
            const float* p = part + (c * 64 + lane) * (KC + 1);
#pragma unroll
            for (int k = 0; k < KC; ++k) d64[k] += (double)p[k];
            z64 += (double)p[KC];
        }

        // argmin with best+second tracking; strict < keeps lowest k
        const double* c2s = c2d + s * KC;  // 128B, scalar loads
        double best = c2s[0] - 2.0 * d64[0];
        double second = 1e300;
        int bk = 0;
#pragma unroll
        for (int k = 1; k < KC; ++k) {
            double sc = c2s[k] - 2.0 * d64[k];
            if (sc < best) { second = best; best = sc; bk = k; }
            else if (sc < second) { second = sc; }
        }
        ids_l[lane] = bk;

        // ---- Exact-fp64 rescue for near-ties (margin < EPS_RESCUE).
        // Whole wave cooperates per flagged token: lane = (cc=lane>>4 dim
        // chunk of 64) x (kk=lane&15 codebook). ~1 rescue per block expected.
        unsigned long long mask = __ballot((second - best) < EPS_RESCUE);
        while (mask) {
            const int t = __ffsll(mask) - 1;
            mask &= mask - 1;
            const int kk = lane & 15, cc = lane >> 4;
            const float* hrow = h + (tok_base + t) * D_FULL + (long)s * DSEG + cc * 64;
            const float* crow = cbseg + kk * DSEG + cc * 64;
            double acc = 0.0;
#pragma unroll
            for (int u = 0; u < 64; u += 4) {
                float4 hz = *(const float4*)(hrow + u);
                float4 cz = *(const float4*)(crow + u);
                acc = fma((double)hz.x, (double)cz.x, acc);
                acc = fma((double)hz.y, (double)cz.y, acc);
                acc = fma((double)hz.z, (double)cz.z, acc);
                acc = fma((double)hz.w, (double)cz.w, acc);
            }
            acc += __shfl_down(acc, 16, 64);
            acc += __shfl_down(acc, 32, 64);      // lanes 0..15: full dot for k=lane
            double sc = c2s[kk] - 2.0 * acc;
            int bkr = kk;
#pragma unroll
            for (int off = 8; off > 0; off >>= 1) {   // min over lanes 0..15,
                double osc = __shfl_xor(sc, off, 64); // lower-k wins ties
                int obk = __shfl_xor(bkr, off, 64);
                if (osc < sc || (osc == sc && obk < bkr)) { sc = osc; bkr = obk; }
            }
            if (lane == 0) ids_l[t] = bkr;
        }

        // final ids (post-rescue); exact in fp32 (<= 61440)
        int bkf = ids_l[lane];
        atomicAdd(&ids_out[tok_base + lane], (float)(bkf << (4 * s)));

        // loss with approx best (|err| < 1e-3 per token: invisible in fp32)
        double mind = z64 + best;
#pragma unroll
        for (int off = 32; off > 0; off >>= 1)
            mind += __shfl_down(mind, off, 64);
        if (lane == 0)
            atomicAdd(loss_out, (float)(mind * (1.25 / 8388608.0)));
    }
    __syncthreads();  // ids_l visible to all waves

    // ---- Phase 2: z write from global cb (L2-resident), 8 rows/wave ----
    const float4* cbf4 = (const float4*)cbseg;
#pragma unroll
    for (int r0 = 0; r0 < 8; ++r0) {
        int r = ch * 8 + r0;
        int k = ids_l[r];                      // wave-uniform broadcast
        float4 v = cbf4[k * 64 + lane];        // 1KB coalesced, L2 hit
        ((float4*)(z_out + (tok_base + r) * D_FULL + (long)s * DSEG))[lane] = v;
    }
}

extern "C" void kernel_launch(void* const* d_in, const int* in_sizes, int n_in,
                              void* d_out, int out_size, void* d_ws, size_t ws_size,
                              hipStream_t stream) {
    const float* h  = (const float*)d_in[0];
    const float* cb = (const float*)d_in[1];

    const int n_h = in_sizes[0];          // 33554432
    const int tokens = n_h / D_FULL;      // 32768

    float* z_out    = (float*)d_out;
    float* ids_out  = z_out + (size_t)n_h;
    float* loss_out = ids_out + tokens;

    double* c2d = (double*)d_ws;          // 64 doubles

    dvq_prep<<<64, 256, 0, stream>>>(cb, c2d, ids_out, loss_out);
    dvq_main<<<(tokens / 64) * SEG, 512, 0, stream>>>(h, cb, c2d, z_out,
                                                      ids_out, loss_out);
}

// Round 7
// 241.467 us; speedup vs baseline: 1.1842x; 1.1416x over previous
//
#include <hip/hip_runtime.h>

// DVQ bottleneck: B=8, N=4096, D=1024, S=4, K=16, d=256, BETA=0.25
// Outputs (flat fp32 in d_out): z[8*4096*1024], ids_packed[32768] (as float),
// vq_total[1].
//
// R12 = R9 structure + R11 numerics (both individually verified):
//   R9  (97us, best): 512thr/8 waves, 64-tok x 1-seg tile, h staged via
//        global_load_lds w=16 with XOR swizzle in the per-lane GLOBAL source
//        address (LDS dest linear), fp32 cb slice in LDS read as wave-uniform
//        b128 broadcasts, arena aliases dead h tile. Conflicts 0.
//   R11 (passed): fp32 chunk dots + fp64 chunk-combine + fp64 scores, with
//        an exact-fp64 wave-cooperative rescue for near-ties (margin<1e-3,
//        ~1/block) -> argmin provably identical to the all-fp64 kernel.
// R11's regression cause (cb reads moved to global: unhideable VMEM latency
// at 36% occ) is reverted -- cb reads return to LDS broadcasts where R9
// proved they're hidden. Expected: R9 minus ~20us of fp64 VALU+cvt.
// If flat vs R9: LDS pipe (~43us, 1088 b128/block) confirmed as the wall ->
// next: T=2 token-blocked layout (halves cb broadcasts) or tile pipelining.

#define D_FULL 1024
#define SEG 4
#define DSEG 256
#define KC 16
#define EPS_RESCUE 1e-3

#define GLOBAL_AS __attribute__((address_space(1)))
#define LDS_AS __attribute__((address_space(3)))

static __device__ __forceinline__ void load_lds16(const void* g, void* l) {
    __builtin_amdgcn_global_load_lds((GLOBAL_AS const unsigned int*)g,
                                     (LDS_AS unsigned int*)l, 16, 0, 0);
}

// Prep (64 blocks x 256): fp64 ||c||^2 per (s,k), zero ids_out + loss
// (d_out/d_ws poisoned 0xAA before every timed launch).
__global__ __launch_bounds__(256) void dvq_prep(const float* __restrict__ cb,
                                                double* __restrict__ c2d,
                                                float* __restrict__ ids_out,
                                                float* __restrict__ loss_out) {
    __shared__ double ws[4];
    const int b = blockIdx.x;    // 0..63 == (s,k) pair
    const int t = threadIdx.x;
    const int lane = t & 63;
    const int w = t >> 6;

    ids_out[b * 512 + t] = 0.0f;
    ids_out[b * 512 + 256 + t] = 0.0f;
    if (b == 0 && t == 0) *loss_out = 0.0f;

    double v = (double)cb[b * 256 + t];
    double sq = v * v;
#pragma unroll
    for (int off = 32; off > 0; off >>= 1)
        sq += __shfl_down(sq, off, 64);
    if (lane == 0) ws[w] = sq;
    __syncthreads();
    if (t == 0) c2d[b] = ws[0] + ws[1] + ws[2] + ws[3];
}

__global__ __launch_bounds__(512, 4) void dvq_main(const float* __restrict__ h,
                                                   const float* __restrict__ cb,
                                                   const double* __restrict__ c2d,
                                                   float* __restrict__ z_out,
                                                   float* __restrict__ ids_out,
                                                   float* __restrict__ loss_out) {
    // hl: 64KB h tile [64 tokens][64 float4], XOR-swizzled (phys = j ^ tok).
    // After compute it is aliased by: part [7][64][17] fp32 = 30464B,
    // ids_l [64] int at byte 30720.
    __shared__ __align__(16) float4 hl[64 * 64];
    __shared__ __align__(16) float cbl[KC * DSEG];  // 16KB fp32 codebook slice

    const int i = threadIdx.x;
    const int lane = i & 63;                           // token within block
    const int w = i >> 6;                              // wave id == d-chunk (0..7)
    const int ch = __builtin_amdgcn_readfirstlane(w);  // wave-uniform SGPR

    const int s = blockIdx.x & 3;                      // segment (R9 mapping)
    const long tok_base = (long)(blockIdx.x >> 2) * 64;

    char* hl_b = (char*)hl;
    char* cbl_b = (char*)cbl;

    // ---- Async staging: 8 h rows + 2 cb KBs per wave (global_load_lds w=16).
    // LDS dest linear; XOR swizzle in the per-lane GLOBAL source address. ----
#pragma unroll
    for (int rr = 0; rr < 8; ++rr) {
        const int r = ch * 8 + rr;
        load_lds16(h + (tok_base + r) * D_FULL + (long)s * DSEG +
                       ((lane ^ r) << 2),
                   hl_b + r * 1024);
    }
#pragma unroll
    for (int half = 0; half < 2; ++half) {
        // wave ch covers cb slice bytes [ch*2048, ch*2048+2048)
        load_lds16(cb + s * (KC * DSEG) + ch * 512 + half * 256 + lane * 4,
                   cbl_b + ch * 2048 + half * 1024);
    }
    __syncthreads();  // compiler drains vmcnt(0) before s_barrier

    // ---- Phase 1: fp32 chunk dots. lane = token, wave = 32-dim chunk.
    // z via swizzled LDS read; cb via wave-uniform LDS b128 broadcasts. ----
    const int tk = lane;

    float dot[KC];
#pragma unroll
    for (int k = 0; k < KC; ++k) dot[k] = 0.0f;
    float ze2 = 0.0f;

#pragma unroll
    for (int j = 0; j < 8; ++j) {
        const int jj = ch * 8 + j;                  // logical float4 col (uniform)
        float4 z4 = hl[tk * 64 + (jj ^ tk)];        // swizzled read
        ze2 = fmaf(z4.x, z4.x, ze2);
        ze2 = fmaf(z4.y, z4.y, ze2);
        ze2 = fmaf(z4.z, z4.z, ze2);
        ze2 = fmaf(z4.w, z4.w, ze2);
#pragma unroll
        for (int k = 0; k < KC; ++k) {
            const float4 c4 = *(const float4*)(cbl + k * DSEG + jj * 4);
            dot[k] = fmaf(z4.x, c4.x, dot[k]);
            dot[k] = fmaf(z4.y, c4.y, dot[k]);
            dot[k] = fmaf(z4.z, c4.z, dot[k]);
            dot[k] = fmaf(z4.w, c4.w, dot[k]);
        }
    }

    // ---- Cross-wave reduction: fp32 partials alias the h tile ----
    __syncthreads();  // all waves finished reading hl
    float* part  = (float*)hl_b;                // [7][64][17] fp32
    int*   ids_l = (int*)(hl_b + 30720);        // [64]

    if (w != 0) {
        float* p = part + ((w - 1) * 64 + lane) * (KC + 1);
#pragma unroll
        for (int k = 0; k < KC; ++k) p[k] = dot[k];
        p[KC] = ze2;
    }
    __syncthreads();

    if (w == 0) {
        // fp64 combine of 8 fp32 chunk-dots: score error <= ~1e-5.
        double d64[KC];
#pragma unroll
        for (int k = 0; k < KC; ++k) d64[k] = (double)dot[k];
        double z64 = (double)ze2;
#pragma unroll
        for (int c = 0; c < 7; ++c) {
            const float* p = part + (c * 64 + lane) * (KC + 1);
#pragma unroll
            for (int k = 0; k < KC; ++k) d64[k] += (double)p[k];
            z64 += (double)p[KC];
        }

        // argmin with best+second tracking; strict < keeps lowest k
        const double* c2s = c2d + s * KC;  // 128B, scalar loads
        double best = c2s[0] - 2.0 * d64[0];
        double second = 1e300;
        int bk = 0;
#pragma unroll
        for (int k = 1; k < KC; ++k) {
            double sc = c2s[k] - 2.0 * d64[k];
            if (sc < best) { second = best; best = sc; bk = k; }
            else if (sc < second) { second = sc; }
        }
        ids_l[lane] = bk;

        // ---- Exact-fp64 rescue for near-ties (margin < EPS_RESCUE).
        // Whole wave cooperates per flagged token: lane = (cc=lane>>4 dim
        // chunk of 64) x (kk=lane&15 codebook). ~1 rescue per block expected.
        const float* cbseg = cb + s * (KC * DSEG);
        unsigned long long mask = __ballot((second - best) < EPS_RESCUE);
        while (mask) {
            const int t = __ffsll(mask) - 1;
            mask &= mask - 1;
            const int kk = lane & 15, cc = lane >> 4;
            const float* hrow = h + (tok_base + t) * D_FULL + (long)s * DSEG + cc * 64;
            const float* crow = cbseg + kk * DSEG + cc * 64;
            double acc = 0.0;
#pragma unroll
            for (int u = 0; u < 64; u += 4) {
                float4 hz = *(const float4*)(hrow + u);
                float4 cz = *(const float4*)(crow + u);
                acc = fma((double)hz.x, (double)cz.x, acc);
                acc = fma((double)hz.y, (double)cz.y, acc);
                acc = fma((double)hz.z, (double)cz.z, acc);
                acc = fma((double)hz.w, (double)cz.w, acc);
            }
            acc += __shfl_down(acc, 16, 64);
            acc += __shfl_down(acc, 32, 64);      // lanes 0..15: full dot for k=lane
            double sc = c2s[kk] - 2.0 * acc;
            int bkr = kk;
#pragma unroll
            for (int off = 8; off > 0; off >>= 1) {   // min over lanes 0..15,
                double osc = __shfl_xor(sc, off, 64); // lower-k wins ties
                int obk = __shfl_xor(bkr, off, 64);
                if (osc < sc || (osc == sc && obk < bkr)) { sc = osc; bkr = obk; }
            }
            if (lane == 0) ids_l[t] = bkr;
        }

        // final ids (post-rescue); exact in fp32 (<= 61440)
        int bkf = ids_l[lane];
        atomicAdd(&ids_out[tok_base + lane], (float)(bkf << (4 * s)));

        // loss with approx best (|err| < 1e-3 per token: invisible in fp32)
        double mind = z64 + best;
#pragma unroll
        for (int off = 32; off > 0; off >>= 1)
            mind += __shfl_down(mind, off, 64);
        if (lane == 0)
            atomicAdd(loss_out, (float)(mind * (1.25 / 8388608.0)));
    }
    __syncthreads();  // ids_l visible to all waves

    // ---- Phase 2: z write from LDS codebook, 8 rows/wave, 1KB coalesced ----
    const float4* cbl4 = (const float4*)cbl;
#pragma unroll
    for (int r0 = 0; r0 < 8; ++r0) {
        int r = ch * 8 + r0;
        int k = ids_l[r];                      // wave-uniform broadcast
        float4 v = cbl4[k * 64 + lane];        // contiguous 1KB, bank-floor
        ((float4*)(z_out + (tok_base + r) * D_FULL + (long)s * DSEG))[lane] = v;
    }
}

extern "C" void kernel_launch(void* const* d_in, const int* in_sizes, int n_in,
                              void* d_out, int out_size, void* d_ws, size_t ws_size,
                              hipStream_t stream) {
    const float* h  = (const float*)d_in[0];
    const float* cb = (const float*)d_in[1];

    const int n_h = in_sizes[0];          // 33554432
    const int tokens = n_h / D_FULL;      // 32768

    float* z_out    = (float*)d_out;
    float* ids_out  = z_out + (size_t)n_h;
    float* loss_out = ids_out + tokens;

    double* c2d = (double*)d_ws;          // 64 doubles

    dvq_prep<<<64, 256, 0, stream>>>(cb, c2d, ids_out, loss_out);
    dvq_main<<<(tokens / 64) * SEG, 512, 0, stream>>>(h, cb, c2d, z_out,
                                                      ids_out, loss_out);
}